// Round 7
// baseline (4797.438 us; speedup 1.0000x reference)
//
#include <hip/hip_runtime.h>
#include <math.h>

// JordanRNN B=128,T=2048,I=128,H=256,O=64.
// 32 WGs x 256 thr (4 waves): 8 batch-columns x 4 hidden-quarters. Weights
// register-resident fp16; amdgpu_waves_per_eu(1,1) pins 1 wave/EU.
// R14: PIPELINED POLLS. R13 (eager publish) gained only ~70cy/step ->
// the residual is poll-retry QUANTIZATION: observations of the packet slot
// happen every ~RT (~900cy); a near-miss costs a full RT idle. Fix: issue
// THREE staggered poll sets during phase A (step top / after x-gates /
// after own-h), check oldest-first with counted waits vmcnt(6)/(3)/(0),
// fall back to the proven R13 retry loop only if all three are stale.
// Observation cadence ~150cy -> overshoot past packet-valid-time drops
// from ~RT to ~150cy. Validation identical to R13 (XOR tear-proof packets,
// epoch>=tgt, oldest-valid-set accept; skew-1 safety: partner cannot
// publish epoch t+1 into the polled slot before seeing our epoch-t
// publish, which follows this acceptance).
// vmcnt bookkeeping: ALL in-loop VMEM is inline asm (x(t+1) prefetch is
// now asm global_load_dwordx4 x2; its regs are retired by the next step's
// vmcnt(6) since they are oldest-in-flight) -> the compiler inserts no
// draining vmcnt(0) of its own into the loop.
// Steady-state outstanding at A-end (issue order): xv(2) + publish store(1)
// + set0(3) + set1(3) + set2(3) = 12 -> vmcnt(6)=xv+store+set0 retired;
// vmcnt(3)=+set1; vmcnt(0)=all. Iter 1: xv(2)+sets(9)=11 -> vmcnt(6)
// retires xv+set0 likewise.
// ws: pay[2 parity][8 col][16 slots][64 lanes]x16B = 262144 B.

#define TSTEPS 2048
#define ISZ 128

typedef _Float16 half8 __attribute__((ext_vector_type(8)));
typedef float f32x4 __attribute__((ext_vector_type(4)));
typedef unsigned int u32;
typedef unsigned int u32x4 __attribute__((ext_vector_type(4)));
typedef unsigned long long u64;

__device__ __forceinline__ f32x4 mfma16(half8 a, half8 b, f32x4 c) {
  return __builtin_amdgcn_mfma_f32_16x16x32_f16(a, b, c, 0, 0, 0);
}
__device__ __forceinline__ float sigm(float x) {
  return __builtin_amdgcn_rcpf(1.f + __expf(-x));
}
__device__ __forceinline__ float tanh_fast(float x) {
  return 1.f - 2.f * __builtin_amdgcn_rcpf(1.f + __expf(2.f * x));
}
__device__ __forceinline__ float asf(u32 u) {
  union { u32 v; float f; } c; c.v = u; return c.f;
}

// ---- MALL packet ops (sc1 = device-coherent, bypasses non-coherent L2s)
__device__ __forceinline__ void st_pkt(void* p, u32x4 v) {
  asm volatile("global_store_dwordx4 %0, %1, off sc1" :: "v"(p), "v"(v) : "memory");
}
__device__ __forceinline__ void ld_pkt3_issue(const void* p1, const void* p2,
                                              const void* p3, u32x4& r1, u32x4& r2,
                                              u32x4& r3) {
  asm volatile("global_load_dwordx4 %0, %3, off sc1\n\t"
               "global_load_dwordx4 %1, %4, off sc1\n\t"
               "global_load_dwordx4 %2, %5, off sc1"
               : "=&v"(r1), "=&v"(r2), "=&v"(r3)
               : "v"(p1), "v"(p2), "v"(p3) : "memory");
}
__device__ __forceinline__ void ld_pkt3_wait(const void* p1, const void* p2,
                                             const void* p3, u32x4& r1, u32x4& r2,
                                             u32x4& r3) {
  asm volatile("global_load_dwordx4 %0, %3, off sc1\n\t"
               "global_load_dwordx4 %1, %4, off sc1\n\t"
               "global_load_dwordx4 %2, %5, off sc1\n\t"
               "s_waitcnt vmcnt(0)"
               : "=&v"(r1), "=&v"(r2), "=&v"(r3)
               : "v"(p1), "v"(p2), "v"(p3) : "memory");
}
// x(t+1) prefetch: 2x16B, plain (non-sc1) asm loads; fire-and-forget.
__device__ __forceinline__ void ld_x2(const float* p, u32x4& x0, u32x4& x1) {
  asm volatile("global_load_dwordx4 %0, %2, off\n\t"
               "global_load_dwordx4 %1, %3, off"
               : "=&v"(x0), "=&v"(x1)
               : "v"(p), "v"(p + 4) : "memory");
}
// packet validity: epoch fresh AND XOR-consistent (tear-proof)
#define PKT_OK(r, tgt) (((r)[2] >= (tgt)) && (((r)[0] ^ (r)[1] ^ (r)[2]) == (r)[3]))
#define SB() __builtin_amdgcn_sched_barrier(0)

__global__ __attribute__((amdgpu_flat_work_group_size(256, 256),
                          amdgpu_waves_per_eu(1, 1)))
void jordan_rnn(const float* __restrict__ xg, const float* __restrict__ w_ih,
                const float* __restrict__ w_hh, const float* __restrict__ b_ih,
                const float* __restrict__ b_hh, const float* __restrict__ fc_w,
                const float* __restrict__ fc_b, float* __restrict__ out,
                unsigned char* __restrict__ ws)
{
  const int tid  = threadIdx.x;
  const int lane = tid & 63;
  const int wv   = tid >> 6;          // wave 0..3
  const int n    = lane & 15;
  const int quad = lane >> 4;
  const int col  = blockIdx.x & 7;    // batch column
  const int q    = blockIdx.x >> 3;   // hidden quarter 0..3
  const int u0   = q * 64 + wv * 16;  // this wave's unit slice
  const int b0   = col * 16;

  unsigned char* pay = ws;

  // act cols: 0..127 = x, 128..191 = y(t-1), 192..447 = h
  __shared__ _Float16 act[16][456];
  {
    unsigned int* za = (unsigned int*)&act[0][0];
    for (int i = tid; i < 3648; i += 256) za[i] = 0u;
  }

  // ---- register-resident weights (fp16 B-fragments: lane holds W[n][k32+quad*8+j])
  half8 wr[14], wz[14], win[6], whn[8], wfc[8];
  {
    const int kq = quad * 8;
    const int ur = u0 + n, uz = 256 + u0 + n, un = 512 + u0 + n;
#pragma unroll
    for (int kk = 0; kk < 6; ++kk) {            // k 0..191: w_ih (x|y)
      const float* pr = w_ih + ur * 192 + kk * 32 + kq;
      const float* pz = w_ih + uz * 192 + kk * 32 + kq;
      const float* pn = w_ih + un * 192 + kk * 32 + kq;
#pragma unroll
      for (int j = 0; j < 8; ++j) {
        wr[kk][j] = (_Float16)pr[j]; wz[kk][j] = (_Float16)pz[j]; win[kk][j] = (_Float16)pn[j];
      }
    }
#pragma unroll
    for (int kk = 0; kk < 8; ++kk) {            // k 192..447: w_hh
      const float* pr = w_hh + ur * 256 + kk * 32 + kq;
      const float* pz = w_hh + uz * 256 + kk * 32 + kq;
      const float* pn = w_hh + un * 256 + kk * 32 + kq;
#pragma unroll
      for (int j = 0; j < 8; ++j) {
        wr[6 + kk][j] = (_Float16)pr[j]; wz[6 + kk][j] = (_Float16)pz[j]; whn[kk][j] = (_Float16)pn[j];
      }
    }
#pragma unroll
    for (int kk = 0; kk < 8; ++kk) {            // fc: rows wv*16+n, all K
      const float* pf = fc_w + (wv * 16 + n) * 256 + kk * 32 + kq;
#pragma unroll
      for (int j = 0; j < 8; ++j) wfc[kk][j] = (_Float16)pf[j];
    }
  }
  const float br   = b_ih[u0 + n] + b_hh[u0 + n];
  const float bz   = b_ih[256 + u0 + n] + b_hh[256 + u0 + n];
  const float bin_ = b_ih[512 + u0 + n];
  const float bhn  = b_hh[512 + u0 + n];
  const float fcb  = fc_b[wv * 16 + n];

  float hprev[4] = {0.f, 0.f, 0.f, 0.f};

  // roles
  const int xr = tid >> 4, xc = tid & 15;       // x stage: row, 8 floats at xc*8
  const int sblk = tid >> 6, srem = tid & 63;   // partner-quarter stage decode
  const int cr = (srem >> 4) * 4;               // column-packet: base row
  const int cc = srem & 15;                     //   col within producer wave slice
  const int ok0 = 6 + 2 * q;                    // own-quarter gate frag idx {ok0,ok0+1}
  const int fk0 = 2 * q;                        // own-quarter fc frag idx {fk0,fk0+1}
  const int q1 = (q + 1) & 3, q2 = (q + 2) & 3, q3 = (q + 3) & 3;

  // packet addresses: [parity 131072][col 16384][(q*4+wv) 1024][lane 16]
  unsigned char* cb0 = pay + (size_t)col * 16384;           // parity 0 col base
  unsigned char* cb1 = cb0 + 131072;                        // parity 1 col base
  const int poff = (q * 4 + wv) * 1024 + lane * 16;         // own publish offset
  const int off1 = (q1 * 4 + sblk) * 1024 + srem * 16;      // partner packet offsets
  const int off2 = (q2 * 4 + sblk) * 1024 + srem * 16;
  const int off3 = (q3 * 4 + sblk) * 1024 + srem * 16;

  const float* xbase = xg + (size_t)(b0 + xr) * TSTEPS * ISZ + xc * 8;
  u32x4 xw0, xw1;                               // x(t) bits for phase-B stage

  // stage x(0) (consumed by phase A of step 1); asm-prefetch x(1)
  {
    float4 a = *(const float4*)xbase, b = *(const float4*)(xbase + 4);
    union { _Float16 h[8]; uint4 u; } pk;
    pk.h[0]=(_Float16)a.x; pk.h[1]=(_Float16)a.y; pk.h[2]=(_Float16)a.z; pk.h[3]=(_Float16)a.w;
    pk.h[4]=(_Float16)b.x; pk.h[5]=(_Float16)b.y; pk.h[6]=(_Float16)b.z; pk.h[7]=(_Float16)b.w;
    *(uint4*)&act[xr][xc * 8] = pk.u;
    ld_x2(xbase + ISZ, xw0, xw1);
  }
  __syncthreads();

  for (int t = 1; t <= TSTEPS; ++t) {
    const u32 tgt = (u32)(t - 1);
    unsigned char* cb = ((t - 1) & 1) ? cb1 : cb0;   // read parity (t-1)&1

    // ---- poll set 0 (oldest) at step top
    u32x4 a1, a2, a3, b1, b2, b3, c1, c2, c3;
    ld_pkt3_issue(cb + off1, cb + off2, cb + off3, a1, a2, a3);

    // ---- A1: x gates (partner-independent)
    f32x4 aR = {0,0,0,0}, aZ = {0,0,0,0}, aIN = {0,0,0,0}, aHN = {0,0,0,0};
    f32x4 accy = {0,0,0,0};
#pragma unroll
    for (int kk = 0; kk < 4; ++kk) {
      half8 af = *(const half8*)&act[n][kk * 32 + quad * 8];
      aR = mfma16(af, wr[kk], aR);
      aZ = mfma16(af, wz[kk], aZ);
      aIN = mfma16(af, win[kk], aIN);
    }
    // ---- poll set 1
    ld_pkt3_issue(cb + off1, cb + off2, cb + off3, b1, b2, b3);

    // ---- A2: own-quarter h gates
#pragma unroll
    for (int kk = 0; kk < 2; ++kk) {
      half8 af = *(const half8*)&act[n][(ok0 + kk) * 32 + quad * 8];
      aR = mfma16(af, wr[ok0 + kk], aR);
      aZ = mfma16(af, wz[ok0 + kk], aZ);
      aHN = mfma16(af, whn[ok0 - 6 + kk], aHN);
    }
    // ---- poll set 2
    ld_pkt3_issue(cb + off1, cb + off2, cb + off3, c1, c2, c3);

    // ---- A3: own-quarter fc (y(t-1) partial)
#pragma unroll
    for (int kk = 0; kk < 2; ++kk) {
      half8 af = *(const half8*)&act[n][192 + (fk0 + kk) * 32 + quad * 8];
      accy = mfma16(af, wfc[fk0 + kk], accy);
    }

    // ---- staged oldest-first validation (fine-grained observation cadence)
    u32x4 r1, r2, r3;
    SB();
    asm volatile("s_waitcnt vmcnt(6)" : "+v"(a1), "+v"(a2), "+v"(a3) :: "memory");
    SB();
    int ok = PKT_OK(a1, tgt) && PKT_OK(a2, tgt) && PKT_OK(a3, tgt);
    if (__all(ok)) {
      r1 = a1; r2 = a2; r3 = a3;
    } else {
      SB();
      asm volatile("s_waitcnt vmcnt(3)" : "+v"(b1), "+v"(b2), "+v"(b3) :: "memory");
      SB();
      ok = PKT_OK(b1, tgt) && PKT_OK(b2, tgt) && PKT_OK(b3, tgt);
      if (__all(ok)) {
        r1 = b1; r2 = b2; r3 = b3;
      } else {
        SB();
        asm volatile("s_waitcnt vmcnt(0)" : "+v"(c1), "+v"(c2), "+v"(c3) :: "memory");
        SB();
        r1 = c1; r2 = c2; r3 = c3;
        ok = PKT_OK(r1, tgt) && PKT_OK(r2, tgt) && PKT_OK(r3, tgt);
        while (!__all(ok)) {
          __builtin_amdgcn_s_sleep(1);
          ld_pkt3_wait(cb + off1, cb + off2, cb + off3, r1, r2, r3);
          ok = PKT_OK(r1, tgt) && PKT_OK(r2, tgt) && PKT_OK(r3, tgt);
        }
      }
    }
    // ---- stage 3 partner h(t-1) quarters into LDS (column-packet layout)
    {
      union { u64 u; _Float16 h[4]; } w1, w2, w3;
      w1.u = ((u64)r1[1] << 32) | r1[0];
      w2.u = ((u64)r2[1] << 32) | r2[0];
      w3.u = ((u64)r3[1] << 32) | r3[0];
#pragma unroll
      for (int r = 0; r < 4; ++r) {
        act[cr + r][192 + q1 * 64 + sblk * 16 + cc] = w1.h[r];
        act[cr + r][192 + q2 * 64 + sblk * 16 + cc] = w2.h[r];
        act[cr + r][192 + q3 * 64 + sblk * 16 + cc] = w3.h[r];
      }
    }
    __syncthreads();  // S1: full h(t-1) staged

    // ---- B: partner-h gates + partner fc; y(t-1); x(t) stage; x(t+1) prefetch
#pragma unroll
    for (int kk = 6; kk < 14; ++kk) {
      if (kk == ok0 || kk == ok0 + 1) continue;
      half8 af = *(const half8*)&act[n][kk * 32 + quad * 8];
      aR = mfma16(af, wr[kk], aR);
      aZ = mfma16(af, wz[kk], aZ);
      aHN = mfma16(af, whn[kk - 6], aHN);
    }
#pragma unroll
    for (int kk = 0; kk < 8; ++kk) {
      if (kk == fk0 || kk == fk0 + 1) continue;
      half8 af = *(const half8*)&act[n][192 + kk * 32 + quad * 8];
      accy = mfma16(af, wfc[kk], accy);
    }
    if (t > 1) {
#pragma unroll
      for (int r = 0; r < 4; ++r)
        act[quad * 4 + r][128 + wv * 16 + n] = (_Float16)tanh_fast(accy[r] + fcb);
    }
    // t==1: y(0)=0 already in act
    {
      // x(t) stage from xw regs (retired: they were oldest at this step's
      // vmcnt(6)); then asm-prefetch x(t+1)
      union { _Float16 h[8]; uint4 u; } pk;
      pk.h[0]=(_Float16)asf(xw0[0]); pk.h[1]=(_Float16)asf(xw0[1]);
      pk.h[2]=(_Float16)asf(xw0[2]); pk.h[3]=(_Float16)asf(xw0[3]);
      pk.h[4]=(_Float16)asf(xw1[0]); pk.h[5]=(_Float16)asf(xw1[1]);
      pk.h[6]=(_Float16)asf(xw1[2]); pk.h[7]=(_Float16)asf(xw1[3]);
      *(uint4*)&act[xr][xc * 8] = pk.u;
      const size_t ts = (t + 1 < TSTEPS) ? (size_t)(t + 1) : (size_t)(TSTEPS - 1);
      ld_x2(xbase + ts * ISZ, xw0, xw1);
    }
    __syncthreads();  // S2: y(t-1) + x(t) staged

    // ---- C: y gates K4-5, gating, EAGER register publish, own-h LDS write
#pragma unroll
    for (int kk = 4; kk < 6; ++kk) {
      half8 af = *(const half8*)&act[n][kk * 32 + quad * 8];
      aR = mfma16(af, wr[kk], aR);
      aZ = mfma16(af, wz[kk], aZ);
      aIN = mfma16(af, win[kk], aIN);
    }
    {
      union { _Float16 h[4]; u64 u; } ph;
#pragma unroll
      for (int r = 0; r < 4; ++r) {
        float rg = sigm(aR[r] + br);
        float zg = sigm(aZ[r] + bz);
        float nn = tanh_fast(aIN[r] + bin_ + rg * (aHN[r] + bhn));
        float hv = (1.f - zg) * nn + zg * hprev[r];
        hprev[r] = hv;
        ph.h[r] = (_Float16)hv;
      }
      // publish own column segment from REGISTERS (epoch t, parity t&1,
      // XOR checksum). Fire-and-forget; consumers validate.
      unsigned char* cbw = (t & 1) ? cb1 : cb0;
      u32x4 pkt;
      pkt[0] = (u32)ph.u; pkt[1] = (u32)(ph.u >> 32); pkt[2] = (u32)t;
      pkt[3] = pkt[0] ^ pkt[1] ^ pkt[2];
      st_pkt(cbw + poff, pkt);
      // then own-quarter LDS write for next step's phase A
#pragma unroll
      for (int r = 0; r < 4; ++r)
        act[quad * 4 + r][192 + u0 + n] = ph.h[r];
    }
    __syncthreads();  // S3: own h(t) quarter complete in act
  }

  // ---- epilogue: h(T) packets were published in the last phase C. Only
  //      q==0 WGs produce out; others exit (their stores complete anyway).
  if (q == 0) {
    const u32 tgt = (u32)TSTEPS;
    unsigned char* cb = (TSTEPS & 1) ? cb1 : cb0;   // parity TSTEPS&1

    u32x4 r1, r2, r3;
    ld_pkt3_issue(cb + off1, cb + off2, cb + off3, r1, r2, r3);

    f32x4 accy = {0,0,0,0};
#pragma unroll
    for (int kk = 0; kk < 2; ++kk) {
      half8 af = *(const half8*)&act[n][192 + (fk0 + kk) * 32 + quad * 8];
      accy = mfma16(af, wfc[fk0 + kk], accy);
    }

    SB();
    asm volatile("s_waitcnt vmcnt(0)" : "+v"(r1), "+v"(r2), "+v"(r3) :: "memory");
    SB();
    {
      int ok = PKT_OK(r1, tgt) && PKT_OK(r2, tgt) && PKT_OK(r3, tgt);
      while (!__all(ok)) {
        __builtin_amdgcn_s_sleep(1);
        ld_pkt3_wait(cb + off1, cb + off2, cb + off3, r1, r2, r3);
        ok = PKT_OK(r1, tgt) && PKT_OK(r2, tgt) && PKT_OK(r3, tgt);
      }
    }
    {
      union { u64 u; _Float16 h[4]; } w1, w2, w3;
      w1.u = ((u64)r1[1] << 32) | r1[0];
      w2.u = ((u64)r2[1] << 32) | r2[0];
      w3.u = ((u64)r3[1] << 32) | r3[0];
#pragma unroll
      for (int r = 0; r < 4; ++r) {
        act[cr + r][192 + q1 * 64 + sblk * 16 + cc] = w1.h[r];
        act[cr + r][192 + q2 * 64 + sblk * 16 + cc] = w2.h[r];
        act[cr + r][192 + q3 * 64 + sblk * 16 + cc] = w3.h[r];
      }
    }
    __syncthreads();

#pragma unroll
    for (int kk = 0; kk < 8; ++kk) {
      if (kk == fk0 || kk == fk0 + 1) continue;
      half8 af = *(const half8*)&act[n][192 + kk * 32 + quad * 8];
      accy = mfma16(af, wfc[kk], accy);
    }
#pragma unroll
    for (int r = 0; r < 4; ++r)
      out[(size_t)(b0 + quad * 4 + r) * 64 + wv * 16 + n] = tanh_fast(accy[r] + fcb);
  }
}

extern "C" void kernel_launch(void* const* d_in, const int* in_sizes, int n_in,
                              void* d_out, int out_size, void* d_ws, size_t ws_size,
                              hipStream_t stream) {
  hipMemsetAsync(d_ws, 0, 262144, stream);  // both parities: epoch 0 + h(0)=0, XOR-valid
  jordan_rnn<<<dim3(32), dim3(256), 0, stream>>>(
      (const float*)d_in[0], (const float*)d_in[1], (const float*)d_in[2],
      (const float*)d_in[3], (const float*)d_in[4], (const float*)d_in[5],
      (const float*)d_in[6], (float*)d_out, (unsigned char*)d_ws);
}